// Round 10
// baseline (406.206 us; speedup 1.0000x reference)
//
#include <hip/hip_runtime.h>
#include <stdint.h>

#define B_    16
#define L_    2048
#define DIN_  1024
#define H_    512
#define NCOL_ 3072          // 2 * H * 3
#define M_    (B_ * L_)     // 32768
#define K_    DIN_          // 1024
#define NCHUNK 16
#define CHUNK  128          // L_ / NCHUNK

typedef unsigned short u16;
typedef __bf16 bf16_t;
typedef bf16_t bf16x8 __attribute__((ext_vector_type(8)));
typedef float  f32x4  __attribute__((ext_vector_type(4)));

__device__ __forceinline__ u16 f2bf(float f) {
  union { float f; uint32_t u; } v; v.f = f;
  return (u16)((v.u + 0x7fffu + ((v.u >> 16) & 1u)) >> 16);  // RNE
}
__device__ __forceinline__ float bf2f(u16 b) {
  union { uint32_t u; float f; } v; v.u = ((uint32_t)b) << 16; return v.f;
}
__device__ __forceinline__ u16 f2h(float f) {
  _Float16 h = (_Float16)f; return *(u16*)&h;
}
__device__ __forceinline__ float h2f(u16 b) {
  _Float16 h = *(_Float16*)&b; return (float)h;
}

// ---------------- x f32 -> bf16 ----------------
__global__ void cvt_x_kernel(const float4* __restrict__ x, ushort4* __restrict__ xb) {
  int i = blockIdx.x * blockDim.x + threadIdx.x;   // exact grid, no bounds
  float4 v = x[i];
  ushort4 o;
  o.x = f2bf(v.x); o.y = f2bf(v.y); o.z = f2bf(v.z); o.w = f2bf(v.w);
  xb[i] = o;
}

// ---------------- W (K x N) -> Wt (N' x K) bf16, rows plane-permuted ----------------
// n' = k*1024 + d*512 + h  (so the GEMM N axis is planar: [xtil | f | r])
__global__ void transpose_w_kernel(const float* __restrict__ W, u16* __restrict__ Wt) {
  __shared__ float s[32][33];
  int n0 = blockIdx.x * 32;   // N tile
  int i0 = blockIdx.y * 32;   // K tile
  int tx = threadIdx.x, ty = threadIdx.y;  // (32, 8)
  #pragma unroll
  for (int y = 0; y < 32; y += 8)
    s[ty + y][tx] = W[(uint64_t)(i0 + ty + y) * NCOL_ + n0 + tx];
  __syncthreads();
  #pragma unroll
  for (int y = 0; y < 32; y += 8) {
    int n = n0 + ty + y;
    int kk = n % 3, d = n / 1536, h = (n % 1536) / 3;
    int np = kk * 1024 + d * 512 + h;
    Wt[(uint64_t)np * K_ + i0 + tx] = f2bf(s[tx][ty + y]);
  }
}

// ---------------- 256x192 GEMM, 12 waves (3/SIMD), free-run, counted vmcnt ----------------
__device__ __forceinline__ void gload_lds16(const void* g, void* lds) {
  __builtin_amdgcn_global_load_lds(
      (const __attribute__((address_space(1))) uint32_t*)g,
      (__attribute__((address_space(3))) uint32_t*)lds, 16, 0, 0);
}

__device__ __forceinline__ bf16x8 lds_rd(const u16* lds, int byteOff) {
  return __builtin_bit_cast(bf16x8, *(const f32x4*)((const char*)lds + byteOff));
}

// R10 rationale: R4-R9 (4 schedules, 2 tiles) all ~250-267us; per-tile time ==
// LDS(~2800cyc) + MFMA(~2480cyc) SERIALIZED. All rounds ran 2 waves/SIMD ->
// when a wave lgkm-waits, its single SIMD partner is in the same phase; no
// third wave to feed the MFMA pipe. Fix: 12 waves (3/SIMD), per-wave 64x64
// (acc=64 AGPR, fits 170-reg budget at 3 waves/SIMD), free-run single barrier
// per K-tile (R7's best schedule), compiler-counted lgkm interleave.
//
// LDS map (bytes), 136 KiB, 1 block/CU:
//   A bufs (2): {0,1} * 32768          -- 256 rows x 64 bf16, 128 B/row; A tile t -> buf t&1
//   B bufs (3): 65536 + {0,1,2}*24576  -- 192 rows x 64 bf16;            B tile t -> buf t%3
// T2 swizzle per 128-B row: phys granule = logical granule ^ (row&7)
//   (linear gload_lds dest + pre-swizzled GLOBAL source; read byte ^= (rr&7)<<4)
//
// Per tile t: issue stageA(t+1) [2-3 loads/wave], stageB(t+2) [2 loads/wave];
//   ds_read bF(8) + per-a aF(2) + 8 MFMA, compiler-interleaved;
//   boundary: vmcnt(2) -> retires A(t+1) (+B(t+1), older); B(t+2)'s 2 loads
//   (each wave's newest) STAY IN FLIGHT across the barrier. Never drains.
// Ledger: RAW A(t)/B(t): staged t-1/t-2, retired by boundary vmcnt of t-1 per
//   wave, barrier orders cross-wave. WAR: stage into Abuf[(t+1)&1] at t top:
//   its readers (tile t-1) completed reads before passing barrier t-1 (lgkm
//   waits precede each MFMA, MFMAs precede barrier). Tail: t=14 stages A(15)
//   only, boundary vmcnt(0); t=15 stages nothing.
__global__ __launch_bounds__(768, 3) void gemm_u_kernel(const u16* __restrict__ A,
                                                        const u16* __restrict__ Bt,
                                                        const float* __restrict__ bfp,
                                                        const float* __restrict__ brp,
                                                        u16* __restrict__ xtilP,
                                                        u16* __restrict__ fP,
                                                        u16* __restrict__ rP) {
  __shared__ __align__(16) u16 lds[69632];       // 136 KiB

  // Block->tile mapping: XCD-chunked M (16 bm per XCD), bm-fast within XCD.
  // Grid 2048 = 8 XCD * (16 bm * 16 bn).
  const int bid = blockIdx.x;
  const int xcd = bid & 7;
  const int li  = bid >> 3;                     // 0..255 within XCD
  const int bm  = xcd * 16 + (li & 15);
  const int bn  = li >> 4;                      // 0..15
  const int m0 = bm * 256, n0 = bn * 192;

  const int tid  = threadIdx.x;
  const int w    = tid >> 6, lane = tid & 63;   // 12 waves
  const int wr   = w >> 2;                      // 0..2?? no: 4M x 3N -> wr = w % 4? use:
  // wave grid 4M x 3N: wr in 0..3 (M), wc in 0..2 (N)
  const int wrM  = w & 3, wcN = w >> 2;         // w = wcN*4 + wrM; wcN 0..2
  const int rr   = lane & 15, hs = lane >> 4;
  const int swzRd = (rr & 7) << 4;
  const int hsOff = hs * 16;

  // staging: chunk c (1 KiB = 8 rows x 128 B): row = c*8 + (lane>>3), granule = lane&7
  const int rSub = lane >> 3;
  const int sCol = ((lane & 7) ^ (lane >> 3)) * 8;   // pre-swizzled source granule

  f32x4 acc[4][4] = {};

  auto stageA = [&](int bufBase, int kt) {      // 32 chunks over 12 waves (2-3 each)
    #pragma unroll
    for (int c = w; c < 32; c += 12)
      gload_lds16(A + (uint64_t)(m0 + c * 8 + rSub) * K_ + kt + sCol,
                  (char*)lds + bufBase + c * 1024);
  };
  auto stageB = [&](int bufBase, int kt) {      // 24 chunks over 12 waves (2 each)
    #pragma unroll
    for (int c = w; c < 24; c += 12)
      gload_lds16(Bt + (uint64_t)(n0 + c * 8 + rSub) * K_ + kt + sCol,
                  (char*)lds + bufBase + c * 1024);
  };

  // prologue: A(0)->Ab0, B(0)->Bb0 (older), B(1)->Bb1 (2 newest, stay in flight)
  stageA(0, 0);
  stageB(65536, 0);
  stageB(65536 + 24576, 64);
  asm volatile("s_waitcnt vmcnt(2)" ::: "memory");
  __builtin_amdgcn_sched_barrier(0);
  __builtin_amdgcn_s_barrier();

  const int aRow0 = wrM * 64;                   // A rows for this wave (within 256)
  const int bRow0 = wcN * 64;                   // B rows for this wave (within 192)

  int b3 = 0;                                    // t % 3
  #pragma unroll 1
  for (int t = 0; t < 16; ++t) {
    const int curA = (t & 1) << 15;
    const int curB = 65536 + b3 * 24576;
    const int b3n2 = (b3 >= 1) ? (b3 - 1) : 2;   // (t+2) % 3

    // issue staging first: A(t+1) then B(t+2) (B's 2 loads are each wave's newest)
    if (t < 15) stageA((~t & 1) << 15, (t + 1) * 64);
    if (t < 14) stageB(65536 + b3n2 * 24576, (t + 2) * 64);

    // fragments + MFMAs, compiler-interleaved with counted lgkm waits
    bf16x8 bF[4][2];
    #pragma unroll
    for (int ni = 0; ni < 4; ++ni)
      #pragma unroll
      for (int ks = 0; ks < 2; ++ks)
        bF[ni][ks] = lds_rd(lds, curB + (bRow0 + ni * 16 + rr) * 128 + ((ks * 64 + hsOff) ^ swzRd));
    #pragma unroll
    for (int a = 0; a < 4; ++a) {
      bf16x8 aF[2];
      #pragma unroll
      for (int ks = 0; ks < 2; ++ks)
        aF[ks] = lds_rd(lds, curA + (aRow0 + a * 16 + rr) * 128 + ((ks * 64 + hsOff) ^ swzRd));
      #pragma unroll
      for (int ni = 0; ni < 4; ++ni)
        #pragma unroll
        for (int ks = 0; ks < 2; ++ks)
          acc[a][ni] = __builtin_amdgcn_mfma_f32_16x16x32_bf16(aF[ks], bF[ni][ks], acc[a][ni], 0, 0, 0);
    }

    // boundary: A(t+1) (and all older) retired; B(t+2)'s 2 loads stay in flight
    if (t < 14) {
      asm volatile("s_waitcnt vmcnt(2)" ::: "memory");
      __builtin_amdgcn_sched_barrier(0);
    } else if (t == 14) {
      asm volatile("s_waitcnt vmcnt(0)" ::: "memory");
      __builtin_amdgcn_sched_barrier(0);
    }
    if (t < 15) __builtin_amdgcn_s_barrier();

    b3 = (b3 + 1 == 3) ? 0 : b3 + 1;
  }

  // epilogue: C/D col = lane&15, row = (lane>>4)*4 + i  [m89-verified].
  // n0 = bn*192 doesn't align to planes, but 16-col fragment groups never cross
  // a 1024 boundary -> plane select is wave-uniform per ni.
  #pragma unroll
  for (int ni = 0; ni < 4; ++ni) {
    const int col = n0 + wcN * 64 + ni * 16 + rr;
    const int kk  = col >> 10;                 // 0: xtil, 1: f, 2: r (uniform per wave/ni)
    const int ch  = col & 1023;
    u16* plane = (kk == 0) ? xtilP : (kk == 1 ? fP : rP);
    const float bias = kk ? ((kk == 1 ? bfp : brp)[ch]) : 0.f;
    #pragma unroll
    for (int mi = 0; mi < 4; ++mi) {
      #pragma unroll
      for (int i = 0; i < 4; ++i) {
        const int row = m0 + wrM * 64 + mi * 16 + hs * 4 + i;
        float v = acc[mi][ni][i];
        if (kk) v = 1.f / (1.f + __expf(-(v + bias)));   // uniform branch
        plane[(uint64_t)row * 1024 + ch] = f2h(v);
      }
    }
  }
}

// ---------------- chunked scan, phase A: per-chunk partial (c0=0) + decay product ----------------
__global__ __launch_bounds__(256) void scan_partial_kernel(const u16* __restrict__ xtilP,
                                                           const u16* __restrict__ fP,
                                                           float* __restrict__ cpart,
                                                           float* __restrict__ Pp) {
  int tid = blockIdx.x * 256 + threadIdx.x;       // 262144 = B * NCHUNK * 1024
  int ch = tid & 1023, chunk = (tid >> 10) & (NCHUNK - 1), b = tid >> 14;
  int d = ch >> 9;
  int l = chunk * CHUNK + (d ? CHUNK - 1 : 0);
  int64_t stride = d ? -1024 : 1024;
  uint64_t base = ((uint64_t)b * L_ + l) * 1024 + ch;
  float c = 0.f, P = 1.f;
  #pragma unroll 4
  for (int it = 0; it < CHUNK; ++it) {
    float f  = h2f(fP[base]);
    float xt = h2f(xtilP[base]);
    c = f * c + (1.f - f) * xt;
    P *= f;
    base += stride;
  }
  int o = (b * NCHUNK + chunk) * 1024 + ch;
  cpart[o] = c;
  Pp[o] = P;
}

// ---------------- phase B: sequential combine across chunks (per channel) ----------------
__global__ void scan_combine_kernel(const float* __restrict__ cpart, const float* __restrict__ Pp,
                                    float* __restrict__ cin, float* __restrict__ outc) {
  int tid = blockIdx.x * blockDim.x + threadIdx.x;  // 16384
  int ch = tid & 1023, b = tid >> 10, d = ch >> 9;
  float c = 0.f;
  for (int i = 0; i < NCHUNK; ++i) {
    int chunk = d ? (NCHUNK - 1 - i) : i;
    int o = (b * NCHUNK + chunk) * 1024 + ch;
    cin[o] = c;
    c = cpart[o] + Pp[o] * c;
  }
  outc[ch * B_ + b] = c;   // c.T layout (2H, B)
}

// ---------------- phase C: re-scan each chunk from true c_in, emit h ----------------
__global__ __launch_bounds__(256) void scan_final_kernel(const u16* __restrict__ xb,
                                                         const u16* __restrict__ xtilP,
                                                         const u16* __restrict__ fP,
                                                         const u16* __restrict__ rP,
                                                         const float* __restrict__ cin,
                                                         float* __restrict__ outh) {
  int tid = blockIdx.x * 256 + threadIdx.x;       // 262144
  int ch = tid & 1023, chunk = (tid >> 10) & (NCHUNK - 1), b = tid >> 14;
  int d = ch >> 9;
  int l = chunk * CHUNK + (d ? CHUNK - 1 : 0);
  int64_t stride = d ? -1024 : 1024;
  uint64_t base = ((uint64_t)b * L_ + l) * 1024 + ch;
  float c = cin[(b * NCHUNK + chunk) * 1024 + ch];
  #pragma unroll 2
  for (int it = 0; it < CHUNK; ++it) {
    float f    = h2f(fP[base]);
    float xt   = h2f(xtilP[base]);
    float rr   = h2f(rP[base]);
    float xres = bf2f(xb[base]);
    c = f * c + (1.f - f) * xt;
    float th = 1.f - 2.f / (__expf(2.f * c) + 1.f);   // tanh
    outh[base] = rr * th + (1.f - rr) * xres;
    base += stride;
  }
}

// ---------------- launch ----------------
extern "C" void kernel_launch(void* const* d_in, const int* in_sizes, int n_in,
                              void* d_out, int out_size, void* d_ws, size_t ws_size,
                              hipStream_t stream) {
  const float* x   = (const float*)d_in[0];
  const float* W   = (const float*)d_in[1];
  const float* bfp = (const float*)d_in[2];
  const float* brp = (const float*)d_in[3];

  float* outh = (float*)d_out;
  float* outc = outh + (size_t)B_ * L_ * DIN_;   // after (B, L, 2H)

  // ws layout (262 MiB total):
  u16* xb = (u16*)d_ws;                          // M_*K_ bf16      = 64 MiB (live: phase-C residual)
  u16* Wt = xb + (size_t)M_ * K_;                // NCOL_*K_ bf16   = 6 MiB (dead after GEMM)
  u16* xtilP = Wt + (size_t)NCOL_ * K_;          // M_*1024 fp16    = 64 MiB
  u16* fP    = xtilP + (size_t)M_ * 1024;        // 64 MiB
  u16* rP    = fP    + (size_t)M_ * 1024;        // 64 MiB
  // chunk-scan scratch aliases the dead Wt region (3 MiB <= 6 MiB):
  float* cpart = (float*)Wt;                     // B*NCHUNK*1024 f32 = 1 MiB
  float* Pp    = cpart + (size_t)B_ * NCHUNK * 1024;
  float* cin   = Pp    + (size_t)B_ * NCHUNK * 1024;

  cvt_x_kernel<<<(M_ * K_ / 4) / 256, 256, 0, stream>>>((const float4*)x, (ushort4*)xb);
  transpose_w_kernel<<<dim3(NCOL_ / 32, K_ / 32), dim3(32, 8), 0, stream>>>(W, Wt);
  gemm_u_kernel<<<(M_ / 256) * (NCOL_ / 192), 768, 0, stream>>>(xb, Wt, bfp, brp, xtilP, fP, rP);
  scan_partial_kernel<<<(B_ * NCHUNK * 1024) / 256, 256, 0, stream>>>(xtilP, fP, cpart, Pp);
  scan_combine_kernel<<<(B_ * 2 * H_) / 256, 256, 0, stream>>>(cpart, Pp, cin, outc);
  scan_final_kernel<<<(B_ * NCHUNK * 1024) / 256, 256, 0, stream>>>(xb, xtilP, fP, rP, cin, outh);
}